// Round 5
// baseline (164.470 us; speedup 1.0000x reference)
//
#include <hip/hip_runtime.h>
#include <math.h>

// out = gelu(rowmean(x@W^T - subtract) + logN) + x
// rowmean(x@W^T)[m] = (1/N) * dot(x[m,:], colsum(W)).  No GEMM needed.

typedef float f4 __attribute__((ext_vector_type(4)));

// Kernel A: wsum[k] = sum_n W[n,k] (atomics over row-chunks).
// Last grid.y slice (blockIdx.x==0) also computes submean = mean(subtract).
__global__ __launch_bounds__(256) void colsum_kernel(
    const float* __restrict__ w, const float* __restrict__ sub,
    float* __restrict__ wsum, float* __restrict__ submean,
    int N, int K, int rows_per_block, float invN) {
    if (blockIdx.y == gridDim.y - 1) {
        if (blockIdx.x != 0) return;
        float acc = 0.f;
        for (int i = threadIdx.x; i < N; i += 256) acc += sub[i];
        #pragma unroll
        for (int off = 32; off > 0; off >>= 1) acc += __shfl_down(acc, off, 64);
        __shared__ float sd[4];
        if ((threadIdx.x & 63) == 0) sd[threadIdx.x >> 6] = acc;
        __syncthreads();
        if (threadIdx.x == 0) submean[0] = (sd[0] + sd[1] + sd[2] + sd[3]) * invN;
        return;
    }
    const int K4 = K >> 2;
    const int col4 = blockIdx.x * blockDim.x + threadIdx.x;
    if (col4 >= K4) return;
    const int row0 = blockIdx.y * rows_per_block;
    int row1 = row0 + rows_per_block;
    if (row1 > N) row1 = N;
    const f4* w4 = (const f4*)w;
    f4 acc = (f4)(0.f);
    for (int n = row0; n < row1; ++n) {
        acc += __builtin_nontemporal_load(&w4[(size_t)n * K4 + col4]);
    }
    float* dst = wsum + (size_t)col4 * 4;
    atomicAdd(dst + 0, acc.x);
    atomicAdd(dst + 1, acc.y);
    atomicAdd(dst + 2, acc.z);
    atomicAdd(dst + 3, acc.w);
}

// Kernel B: one wave per row, TWO streaming passes over the row.
// Pass 1: cacheable x loads -> dot (nothing held live).  Shuffle reduce.
// Pass 2: re-load x (L2/L3 hit -- row touched microseconds ago), add g,
// nontemporal store.  Memory clobber between passes stops the compiler
// from CSE-ing pass 2's loads into register residency (the R4 mistake).
// Low VGPR -> 8 waves/SIMD (the occupancy cap).
__global__ __launch_bounds__(256, 8) void fused_row_kernel(
    const float* __restrict__ x, const float* __restrict__ wsum,
    const float* __restrict__ submean_p, float* __restrict__ out,
    int M, int K, float logN, float invN) {
    const int lane = threadIdx.x & 63;
    const int row = blockIdx.x * 4 + (threadIdx.x >> 6);
    if (row >= M) return;
    const f4* x4 = (const f4*)(x + (size_t)row * K);
    const f4* ws4 = (const f4*)wsum;

    float dot = 0.f;
    #pragma unroll 4
    for (int j = 0; j < 16; ++j) {
        const int idx = j * 64 + lane;               // coalesced per wave
        const f4 xx = x4[idx];                       // cacheable (re-read below)
        const f4 ww = ws4[idx];                      // L1-resident (16 KB)
        dot = fmaf(xx.x, ww.x, fmaf(xx.y, ww.y,
              fmaf(xx.z, ww.z, fmaf(xx.w, ww.w, dot))));
    }

    #pragma unroll
    for (int off = 1; off < 64; off <<= 1) dot += __shfl_xor(dot, off, 64);

    const float c = dot * invN - submean_p[0] + logN;
    const float t = 0.7978845608028654f * fmaf(0.044715f * c, c * c, c);
    const float g = 0.5f * c * (1.f + t / (fabsf(t) + 1.f));

    asm volatile("" ::: "memory");                   // force re-load, not CSE

    f4* o4 = (f4*)(out + (size_t)row * K);
    #pragma unroll 4
    for (int j = 0; j < 16; ++j) {
        const int idx = j * 64 + lane;
        const f4 xx = x4[idx];                       // L2/L3 hit
        __builtin_nontemporal_store(xx + (f4)(g), &o4[idx]);
    }
}

extern "C" void kernel_launch(void* const* d_in, const int* in_sizes, int n_in,
                              void* d_out, int out_size, void* d_ws, size_t ws_size,
                              hipStream_t stream) {
    const float* x   = (const float*)d_in[0];
    const float* w   = (const float*)d_in[1];
    const float* sub = (const float*)d_in[2];
    float* out = (float*)d_out;

    const int N = in_sizes[2];            // 4096
    const int K = in_sizes[1] / N;        // 4096
    const int M = in_sizes[0] / K;        // 16384

    float* wsum    = (float*)d_ws;        // K floats
    float* submean = wsum + K;            // 1 float

    (void)hipMemsetAsync(d_ws, 0, (size_t)(K + 1) * sizeof(float), stream);

    const int K4 = K / 4;
    const int rows_per_block = 16;        // more chunks -> better TLP on W pass
    dim3 gA((K4 + 255) / 256, N / rows_per_block + 1);
    colsum_kernel<<<gA, 256, 0, stream>>>(w, sub, wsum, submean,
                                          N, K, rows_per_block, 1.0f / (float)N);

    fused_row_kernel<<<M / 4, 256, 0, stream>>>(
        x, wsum, submean, out, M, K, logf((float)N), 1.0f / (float)N);
}

// Round 6
// 140.505 us; speedup vs baseline: 1.1706x; 1.1706x over previous
//
#include <hip/hip_runtime.h>
#include <math.h>

// out = gelu(rowmean(x@W^T - subtract) + logN) + x
// rowmean(x@W^T)[m] = (1/N) * dot(x[m,:], colsum(W)).  No GEMM needed.

typedef float f4 __attribute__((ext_vector_type(4)));

// Kernel A: wsum[k] = sum_n W[n,k] (atomics over row-chunks).
// Last grid.y slice (blockIdx.x==0) also computes submean = mean(subtract).
__global__ __launch_bounds__(256) void colsum_kernel(
    const float* __restrict__ w, const float* __restrict__ sub,
    float* __restrict__ wsum, float* __restrict__ submean,
    int N, int K, int rows_per_block, float invN) {
    if (blockIdx.y == gridDim.y - 1) {
        if (blockIdx.x != 0) return;
        float acc = 0.f;
        for (int i = threadIdx.x; i < N; i += 256) acc += sub[i];
        #pragma unroll
        for (int off = 32; off > 0; off >>= 1) acc += __shfl_down(acc, off, 64);
        __shared__ float sd[4];
        if ((threadIdx.x & 63) == 0) sd[threadIdx.x >> 6] = acc;
        __syncthreads();
        if (threadIdx.x == 0) submean[0] = (sd[0] + sd[1] + sd[2] + sd[3]) * invN;
        return;
    }
    const int K4 = K >> 2;
    const int col4 = blockIdx.x * blockDim.x + threadIdx.x;
    if (col4 >= K4) return;
    const int row0 = blockIdx.y * rows_per_block;
    int row1 = row0 + rows_per_block;
    if (row1 > N) row1 = N;
    const f4* w4 = (const f4*)w;
    f4 acc = (f4)(0.f);
    for (int n = row0; n < row1; ++n) {
        acc += __builtin_nontemporal_load(&w4[(size_t)n * K4 + col4]);
    }
    float* dst = wsum + (size_t)col4 * 4;
    atomicAdd(dst + 0, acc.x);
    atomicAdd(dst + 1, acc.y);
    atomicAdd(dst + 2, acc.z);
    atomicAdd(dst + 3, acc.w);
}

// Kernel B: HALF a row per wave (8 float4/lane register-resident), 2 rows
// per 256-thread block.  Wave-reduce + one tiny LDS combine of the two
// half-row partials.  Low VGPR (~60) -> 8 waves/SIMD, while x stays in
// registers for the store phase (R3 showed register residency beats L2
// re-read; R4 showed too MUCH residency kills occupancy).
__global__ __launch_bounds__(256, 8) void fused_row_kernel(
    const float* __restrict__ x, const float* __restrict__ wsum,
    const float* __restrict__ submean_p, float* __restrict__ out,
    int M, int K, float logN, float invN) {
    const int lane   = threadIdx.x & 63;
    const int wave   = threadIdx.x >> 6;   // 0..3
    const int rlocal = wave >> 1;          // 0..1 : row within block
    const int half   = wave & 1;           // 0..1 : which half-row
    const int row = blockIdx.x * 2 + rlocal;
    const int K4 = K >> 2;                 // 1024
    const int H4 = K4 >> 1;                // 512 f4 per half-row
    const int PJ = H4 >> 6;                // 8 f4 per lane

    const f4* x4  = (const f4*)(x + (size_t)row * K) + (size_t)half * H4;
    const f4* ws4 = (const f4*)wsum + (size_t)half * H4;

    f4 xv[8];
    #pragma unroll
    for (int j = 0; j < 8; ++j)
        xv[j] = __builtin_nontemporal_load(&x4[j * 64 + lane]);

    float dot = 0.f;
    #pragma unroll
    for (int j = 0; j < 8; ++j) {
        const f4 ww = ws4[j * 64 + lane];  // L1-resident (16 KB total)
        dot = fmaf(xv[j].x, ww.x, fmaf(xv[j].y, ww.y,
              fmaf(xv[j].z, ww.z, fmaf(xv[j].w, ww.w, dot))));
    }
    (void)PJ;

    #pragma unroll
    for (int off = 1; off < 64; off <<= 1) dot += __shfl_xor(dot, off, 64);

    __shared__ float sd[4];
    if (lane == 0) sd[wave] = dot;
    __syncthreads();
    const float total = sd[rlocal * 2] + sd[rlocal * 2 + 1];

    const float c = total * invN - submean_p[0] + logN;
    const float t = 0.7978845608028654f * fmaf(0.044715f * c, c * c, c);
    const float g = 0.5f * c * (1.f + t / (fabsf(t) + 1.f));

    f4* o4 = (f4*)(out + (size_t)row * K) + (size_t)half * H4;
    #pragma unroll
    for (int j = 0; j < 8; ++j)
        __builtin_nontemporal_store(xv[j] + (f4)(g), &o4[j * 64 + lane]);
    (void)M;
}

extern "C" void kernel_launch(void* const* d_in, const int* in_sizes, int n_in,
                              void* d_out, int out_size, void* d_ws, size_t ws_size,
                              hipStream_t stream) {
    const float* x   = (const float*)d_in[0];
    const float* w   = (const float*)d_in[1];
    const float* sub = (const float*)d_in[2];
    float* out = (float*)d_out;

    const int N = in_sizes[2];            // 4096
    const int K = in_sizes[1] / N;        // 4096
    const int M = in_sizes[0] / K;        // 16384

    float* wsum    = (float*)d_ws;        // K floats
    float* submean = wsum + K;            // 1 float

    (void)hipMemsetAsync(d_ws, 0, (size_t)(K + 1) * sizeof(float), stream);

    const int K4 = K / 4;
    const int rows_per_block = 16;
    dim3 gA((K4 + 255) / 256, N / rows_per_block + 1);
    colsum_kernel<<<gA, 256, 0, stream>>>(w, sub, wsum, submean,
                                          N, K, rows_per_block, 1.0f / (float)N);

    // 2 rows per block (2 waves per row)
    fused_row_kernel<<<M / 2, 256, 0, stream>>>(
        x, wsum, submean, out, M, K, logf((float)N), 1.0f / (float)N);
}